// Round 14
// baseline (70.145 us; speedup 1.0000x reference)
//
#include <hip/hip_runtime.h>
#include <hip/hip_bf16.h>

#define NN     200000
#define FEATD  64
#define BN     4096
#define DEG    32
#define PP     2048
#define EMB    64
#define EPSV   1e-8f
#define NTILE64 3125       // NN / 64 exactly

// ws layout (float offsets)
#define WS_SC    0          // float4[NN]  {s0,s1,s2,norm}
#define WS_PL    1000000    // per-wave loss partials: [12288][2] = (S1,S2)
#define WS_RF    1100000    // [3][BN][EMB]

typedef short  bf16x8 __attribute__((ext_vector_type(8)));
typedef float  f32x4  __attribute__((ext_vector_type(4)));

// RNE f32 -> bf16 (returns rounded bits in high 16, mask applied)
__device__ __forceinline__ unsigned int bfr(float x) {
    unsigned int u = __float_as_uint(x);
    return (u + 0x7FFFu + ((u >> 16) & 1u)) & 0xFFFF0000u;
}

// ---------------------------------------------------------------- kernel A
// sim = relu(F @ R) per node via MFMA, hi/lo bf16 split (6 passes).
// ONE TILE PER WAVE (grid 782 x 4 waves ~= 3125 tiles): no loop, no
// prefetch, no 2-vs-1 tile imbalance. Experiment: if per-tile cost is the
// modeled ~3.5k cyc, A collapses to ~6-9us; if not, the cost is intrinsic
// to the tile body and next step is bisection.
__global__ __launch_bounds__(256, 2) void node_precompute(
    const float* __restrict__ features, const float* __restrict__ rsim,
    const float* __restrict__ pos_embs, float4* __restrict__ node_sc)
{
    __shared__ unsigned int lds[4][2][8][64][4];   // [wave][hi/lo][kg][node'][16B]
    __shared__ float4 trp[4][16][16];              // [wave][node][swz col]
    int t = threadIdx.x, w = t >> 6, l = t & 63;
    int tile = blockIdx.x * 4 + w;
    if (tile >= NTILE64) return;
    int lg = l >> 4;          // k-group / node-group-of-4
    int lr = l & 15;          // A-row / B-col within fragment
    const float4* Gf = (const float4*)features;

    // ---- R fragments (hi/lo)
    bf16x8 rhi[2][4], rlo[2][4];
#pragma unroll
    for (int kk = 0; kk < 2; ++kk)
#pragma unroll
        for (int nf = 0; nf < 4; ++nf) {
            union { unsigned int u[4]; bf16x8 v; } H, L;
#pragma unroll
            for (int i = 0; i < 4; ++i) {
                int k0 = kk * 32 + lg * 8 + i * 2;
                int j  = nf * 16 + lr;
                float x0 = rsim[k0 * 64 + j];
                float x1 = rsim[(k0 + 1) * 64 + j];
                unsigned int r0 = bfr(x0), r1 = bfr(x1);
                H.u[i] = (r0 >> 16) | r1;
                float l0 = x0 - __uint_as_float(r0);
                float l1 = x1 - __uint_as_float(r1);
                L.u[i] = (__float_as_uint(l0) >> 16)
                       | (__float_as_uint(l1) & 0xFFFF0000u);
            }
            rhi[kk][nf] = H.v; rlo[kk][nf] = L.v;
        }

    float pe[3][4];
#pragma unroll
    for (int rr = 0; rr < 3; ++rr)
#pragma unroll
        for (int nf = 0; nf < 4; ++nf)
            pe[rr][nf] = pos_embs[rr * 64 + nf * 16 + lr];

    unsigned int (*Lhi)[64][4] = lds[w][0];
    unsigned int (*Llo)[64][4] = lds[w][1];
    float4 (*T)[16] = trp[w];

    // ---- load + split + LDS write
    const float4* src = Gf + (size_t)tile * 1024;
#pragma unroll
    for (int s = 0; s < 16; ++s) {
        float4 v = src[s * 64 + l];
        int node = s * 4 + lg;
        int kg = lr >> 1, half = lr & 1;
        unsigned int rx = bfr(v.x), ry = bfr(v.y);
        unsigned int rz = bfr(v.z), rw = bfr(v.w);
        unsigned int h0 = (rx >> 16) | ry;
        unsigned int h1 = (rz >> 16) | rw;
        float lx = v.x - __uint_as_float(rx), ly = v.y - __uint_as_float(ry);
        float lz = v.z - __uint_as_float(rz), lw = v.w - __uint_as_float(rw);
        unsigned int l0 = (__float_as_uint(lx) >> 16)
                        | (__float_as_uint(ly) & 0xFFFF0000u);
        unsigned int l1 = (__float_as_uint(lz) >> 16)
                        | (__float_as_uint(lw) & 0xFFFF0000u);
        uint2* dh = (uint2*)&Lhi[kg][node ^ kg][half * 2];
        uint2* dl = (uint2*)&Llo[kg][node ^ kg][half * 2];
        *dh = make_uint2(h0, h1);
        *dl = make_uint2(l0, l1);
    }

    const bf16x8* ph = (const bf16x8*)Lhi;
    const bf16x8* pl = (const bf16x8*)Llo;

#pragma unroll
    for (int mf = 0; mf < 4; ++mf) {
        int node = mf * 16 + lr;
        bf16x8 ah0 = ph[lg * 64 + (node ^ lg)];
        bf16x8 ah1 = ph[(4 + lg) * 64 + (node ^ (4 + lg))];
        bf16x8 al0 = pl[lg * 64 + (node ^ lg)];
        bf16x8 al1 = pl[(4 + lg) * 64 + (node ^ (4 + lg))];

        f32x4 acc[4];
#pragma unroll
        for (int nf = 0; nf < 4; ++nf) acc[nf] = (f32x4)(0.f);
#pragma unroll
        for (int nf = 0; nf < 4; ++nf) {
            acc[nf] = __builtin_amdgcn_mfma_f32_16x16x32_bf16(
                          ah0, rhi[0][nf], acc[nf], 0, 0, 0);
            acc[nf] = __builtin_amdgcn_mfma_f32_16x16x32_bf16(
                          ah1, rhi[1][nf], acc[nf], 0, 0, 0);
            acc[nf] = __builtin_amdgcn_mfma_f32_16x16x32_bf16(
                          ah0, rlo[0][nf], acc[nf], 0, 0, 0);
            acc[nf] = __builtin_amdgcn_mfma_f32_16x16x32_bf16(
                          ah1, rlo[1][nf], acc[nf], 0, 0, 0);
            acc[nf] = __builtin_amdgcn_mfma_f32_16x16x32_bf16(
                          al0, rhi[0][nf], acc[nf], 0, 0, 0);
            acc[nf] = __builtin_amdgcn_mfma_f32_16x16x32_bf16(
                          al1, rhi[1][nf], acc[nf], 0, 0, 0);
        }

        // ---- epilogue: per-reg dots -> LDS transpose -> 4-lane reduce
#pragma unroll
        for (int reg = 0; reg < 4; ++reg) {
            float s0 = 0.f, s1 = 0.f, s2 = 0.f, q = 0.f;
#pragma unroll
            for (int nf = 0; nf < 4; ++nf) {
                float v = fmaxf(acc[nf][reg], 0.f);
                s0 += v * pe[0][nf];
                s1 += v * pe[1][nf];
                s2 += v * pe[2][nf];
                q  += v * v;
            }
            int nd = lg * 4 + reg;
            T[nd][(lr + nd) & 15] = make_float4(s0, s1, s2, q);
        }
        int rn = l >> 2, rq = l & 3;
        float4 a0 = T[rn][(rq * 4 + 0 + rn) & 15];
        float4 a1 = T[rn][(rq * 4 + 1 + rn) & 15];
        float4 a2 = T[rn][(rq * 4 + 2 + rn) & 15];
        float4 a3 = T[rn][(rq * 4 + 3 + rn) & 15];
        float sx = a0.x + a1.x + a2.x + a3.x;
        float sy = a0.y + a1.y + a2.y + a3.y;
        float sz = a0.z + a1.z + a2.z + a3.z;
        float sw = a0.w + a1.w + a2.w + a3.w;
#pragma unroll
        for (int o = 1; o < 4; o <<= 1) {
            sx += __shfl_xor(sx, o);
            sy += __shfl_xor(sy, o);
            sz += __shfl_xor(sz, o);
            sw += __shfl_xor(sw, o);
        }
        if (rq == 0)
            node_sc[tile * 64 + mf * 16 + rn] =
                make_float4(sx, sy, sz, sqrtf(sw));
    }
}

// ---------------------------------------------------------------- kernel C
// One wave per (b, r): inv_pe computed locally (6 shfl); score, stable
// top-k, parallel aggregate, rfeat = relu(agg @ W_r). Loss partials
// (S1=sum sp, S2=sum sp^2) written to PRIVATE per-wave slots — no atomics,
// no zeroing, no dependency on a stats kernel.
__global__ __launch_bounds__(256) void relation_agg(
    const int* __restrict__ n1, const int* __restrict__ n2, const int* __restrict__ n3,
    const float* __restrict__ features, const float4* __restrict__ node_sc,
    const float* __restrict__ W1, const float* __restrict__ W2, const float* __restrict__ W3,
    const float* __restrict__ pos_embs, float* __restrict__ plossws,
    float* __restrict__ rfeat, const int* __restrict__ smp)
{
    int r = blockIdx.y;
    const int*   neigh = (r == 0) ? n1 : (r == 1) ? n2 : n3;
    const float* W     = (r == 0) ? W1 : (r == 1) ? W2 : W3;
    int k = smp[0];
    int t = threadIdx.x;
    int wv = t >> 6, lane = t & 63;
    int b = blockIdx.x * 4 + wv;

    __shared__ int sel_ids[4][32];
    __shared__ float4 aggl[4][16];

    // ---- inv_pe for this relation (all lanes)
    float pv = pos_embs[r * 64 + lane];
    float qq = pv * pv;
#pragma unroll
    for (int o = 1; o < 64; o <<= 1) qq += __shfl_xor(qq, o);
    float inv_pe = 1.f / fmaxf(sqrtf(qq), EPSV);

    // ---- score phase (lanes 0-31)
    float s = -1e30f;
    int   n = 0;
    if (lane < 32) {
        n = neigh[b * DEG + lane];
        float4 sc = node_sc[n];
        float num = (r == 0) ? sc.x : (r == 1) ? sc.y : sc.z;
        s = num * inv_pe / fmaxf(sc.w, EPSV);
    }
    // stable rank among 32 scores (ties -> lower index), matches lax.top_k
    int cnt = 0;
#pragma unroll
    for (int d2 = 0; d2 < 32; ++d2) {
        float v = __shfl(s, d2);
        cnt += ((v > s) || (v == s && d2 < lane)) ? 1 : 0;
    }
    bool sel = (lane < 32) && (cnt < k);
    if (sel) sel_ids[wv][cnt] = n;       // rank = unique slot in [0,k)

    float sp = sel ? s : 0.f;
    float sq = sel ? s * s : 0.f;
#pragma unroll
    for (int off = 32; off; off >>= 1) {
        sp += __shfl_down(sp, off);
        sq += __shfl_down(sq, off);
    }
    if (lane == 0) {
        int wid = (r * 1024 + blockIdx.x) * 4 + wv;   // 0..12287
        plossws[wid * 2]     = sp;
        plossws[wid * 2 + 1] = sq;
    }
    // no __syncthreads: sel_ids producer/consumer are the same wave (lgkmcnt)

    // ---- aggregate phase: 16 lanes per row, 4 rows per load wavefront
    const float4* F = (const float4*)features;
    int col   = lane & 15;           // float4 index within a 64-float row
    int rbase = lane >> 4;           // 0..3
    float4 a = make_float4(0.f, 0.f, 0.f, 0.f);
    if (k == 16) {
        int nid0 = sel_ids[wv][rbase];
        int nid1 = sel_ids[wv][rbase + 4];
        int nid2 = sel_ids[wv][rbase + 8];
        int nid3 = sel_ids[wv][rbase + 12];
        float4 v0 = F[(size_t)nid0 * 16 + col];
        float4 v1 = F[(size_t)nid1 * 16 + col];
        float4 v2 = F[(size_t)nid2 * 16 + col];
        float4 v3 = F[(size_t)nid3 * 16 + col];
        a.x = v0.x + v1.x + v2.x + v3.x;
        a.y = v0.y + v1.y + v2.y + v3.y;
        a.z = v0.z + v1.z + v2.z + v3.z;
        a.w = v0.w + v1.w + v2.w + v3.w;
    } else {
        for (int row0 = 0; row0 < k; row0 += 4) {
            int row = row0 + rbase;
            if (row < k) {
                int nid = sel_ids[wv][row];
                float4 v = F[(size_t)nid * 16 + col];
                a.x += v.x; a.y += v.y; a.z += v.z; a.w += v.w;
            }
        }
    }
    // allreduce across the 4 row-groups (xor 16, 32)
#pragma unroll
    for (int off = 16; off <= 32; off <<= 1) {
        a.x += __shfl_xor(a.x, off);
        a.y += __shfl_xor(a.y, off);
        a.z += __shfl_xor(a.z, off);
        a.w += __shfl_xor(a.w, off);
    }
    float inv_k = 1.f / (float)k;
    a.x *= inv_k; a.y *= inv_k; a.z *= inv_k; a.w *= inv_k;

    // publish agg to LDS (lanes 0-15 hold cols 0..15)
    if (lane < 16) aggl[wv][lane] = a;
    // same-wave producer/consumer: compiler inserts lgkmcnt, no barrier

    // ---- rfeat[e=lane] = relu(sum_j agg[j] * W[j][e]) via uniform LDS reads
    float acc = 0.f;
#pragma unroll
    for (int j4 = 0; j4 < 16; ++j4) {
        float4 ag = aggl[wv][j4];            // wave-uniform -> broadcast
        acc += ag.x * W[(j4 * 4 + 0) * EMB + lane]
             + ag.y * W[(j4 * 4 + 1) * EMB + lane]
             + ag.z * W[(j4 * 4 + 2) * EMB + lane]
             + ag.w * W[(j4 * 4 + 3) * EMB + lane];
    }
    rfeat[((size_t)r * BN + b) * EMB + lane] = fmaxf(acc, 0.f);
}

// ---------------------------------------------------------------- kernel D
// combined[e][b] = relu(cat[b] . weight[:,e]); block 0 additionally computes
// pe norms + mean_pos (2048 gathers) + reduces C's per-wave loss partials
// and writes the loss scalar: loss_r = S2/N - 2*mp*S1/N + mp^2, N = BN*k.
#define CSTRIDE 264
__global__ __launch_bounds__(256) void final_mm(
    const int* __restrict__ nodes, const float* __restrict__ features,
    const float* __restrict__ rfeat, const float* __restrict__ weight,
    const float* __restrict__ pos_embs, const int* __restrict__ pos_nodes,
    const float4* __restrict__ node_sc, const float* __restrict__ plossws,
    const int* __restrict__ smp, float* __restrict__ out)
{
    __shared__ float cat_b[8 * CSTRIDE];   // cat_b[bb][i]
    __shared__ float trans[8 * 65];        // output transpose tile
    __shared__ float invpe_sm[3];
    __shared__ float wsum[4][3];
    __shared__ float lsum[4][3][2];
    int t = threadIdx.x;
    int wv = t >> 6, lane = t & 63;
    int b0 = blockIdx.x * 8;

    // stage cat columns: center features then 3 rfeat blocks
    for (int idx = t; idx < 512; idx += 256) {
        int bb = idx >> 6, f = idx & 63;
        cat_b[bb * CSTRIDE + f] = features[(size_t)nodes[b0 + bb] * FEATD + f];
    }
#pragma unroll
    for (int r = 0; r < 3; ++r)
        for (int idx = t; idx < 512; idx += 256) {
            int bb = idx >> 6, j = idx & 63;
            cat_b[bb * CSTRIDE + 64 + r * 64 + j] =
                rfeat[((size_t)r * BN + b0 + bb) * EMB + j];
        }
    __syncthreads();

    int bb0 = wv * 2;                  // lane = e
    float acc0 = 0.f, acc1 = 0.f;
    const float* c0p = &cat_b[bb0 * CSTRIDE];
    const float* c1p = &cat_b[(bb0 + 1) * CSTRIDE];
    for (int i0 = 0; i0 < 256; i0 += 16) {
        float w[16];
#pragma unroll
        for (int u = 0; u < 16; ++u)
            w[u] = weight[(i0 + u) * EMB + lane];   // coalesced
#pragma unroll
        for (int u = 0; u < 16; ++u) {
            acc0 += w[u] * c0p[i0 + u];             // uniform LDS broadcast
            acc1 += w[u] * c1p[i0 + u];
        }
    }
    trans[bb0 * 65 + lane]       = fmaxf(acc0, 0.f);
    trans[(bb0 + 1) * 65 + lane] = fmaxf(acc1, 0.f);
    __syncthreads();

    // store: out[e][b0..b0+8]
    for (int idx = t; idx < 512; idx += 256) {
        int e = idx >> 3, bb = idx & 7;
        out[(size_t)e * BN + b0 + bb] = trans[bb * 65 + e];
    }

    if (blockIdx.x != 0) return;

    // ================= block 0: loss tail =================
    // phase 1: pe inverse norms (waves 0-2 own rows 0-2)
    float pv = (t < 192) ? pos_embs[t] : 0.f;
    float q = pv * pv;
#pragma unroll
    for (int o = 1; o < 64; o <<= 1) q += __shfl_xor(q, o);
    if (t < 192 && lane == 0)
        invpe_sm[wv] = 1.f / fmaxf(sqrtf(q), EPSV);
    __syncthreads();

    // phase 2: mean_pos over 2048 pos nodes
    float m0 = 0.f, m1 = 0.f, m2 = 0.f;
    for (int p = t; p < PP; p += 256) {
        int n = pos_nodes[p];
        float4 sc = node_sc[n];
        float invn = 1.f / fmaxf(sc.w, EPSV);
        m0 += sc.x * invpe_sm[0] * invn;
        m1 += sc.y * invpe_sm[1] * invn;
        m2 += sc.z * invpe_sm[2] * invn;
    }
#pragma unroll
    for (int o = 1; o < 64; o <<= 1) {
        m0 += __shfl_xor(m0, o);
        m1 += __shfl_xor(m1, o);
        m2 += __shfl_xor(m2, o);
    }
    if (lane == 0) { wsum[wv][0] = m0; wsum[wv][1] = m1; wsum[wv][2] = m2; }

    // phase 3: reduce per-wave loss partials (each wave handles one r; wave 3 idle)
    if (wv < 3) {
        float s1 = 0.f, s2 = 0.f;
        const float2* pl2 = (const float2*)plossws;
        for (int i = lane; i < 4096; i += 64) {
            float2 v = pl2[wv * 4096 + i];
            s1 += v.x; s2 += v.y;
        }
#pragma unroll
        for (int o = 1; o < 64; o <<= 1) {
            s1 += __shfl_xor(s1, o);
            s2 += __shfl_xor(s2, o);
        }
        if (lane == 0) { lsum[0][wv][0] = s1; lsum[0][wv][1] = s2; }
    }
    __syncthreads();

    if (t == 0) {
        int k = smp[0];
        float N = (float)BN * (float)k;
        float loss = 0.f;
#pragma unroll
        for (int r = 0; r < 3; ++r) {
            float mp = (wsum[0][r] + wsum[1][r] + wsum[2][r] + wsum[3][r])
                       / (float)PP;
            float s1 = lsum[0][r][0], s2 = lsum[0][r][1];
            loss += s2 / N - 2.f * mp * s1 / N + mp * mp;
        }
        out[(size_t)EMB * BN] = loss / 3.f;
    }
}

// ----------------------------------------------------------------
extern "C" void kernel_launch(void* const* d_in, const int* in_sizes, int n_in,
                              void* d_out, int out_size, void* d_ws, size_t ws_size,
                              hipStream_t stream) {
    const int*   nodes     = (const int*)  d_in[0];
    // d_in[1] labels: unused
    const int*   neigh1    = (const int*)  d_in[2];
    const int*   neigh2    = (const int*)  d_in[3];
    const int*   neigh3    = (const int*)  d_in[4];
    const int*   pos_nodes = (const int*)  d_in[5];
    const float* features  = (const float*)d_in[6];
    const float* weight    = (const float*)d_in[7];
    const float* rsim      = (const float*)d_in[8];
    const float* pos_embs  = (const float*)d_in[9];
    const float* W1        = (const float*)d_in[10];
    const float* W2        = (const float*)d_in[11];
    const float* W3        = (const float*)d_in[12];
    const int*   smp       = (const int*)  d_in[13];
    float* out = (float*)d_out;
    float* ws  = (float*)d_ws;

    float4* node_sc = (float4*)(ws + WS_SC);
    float*  plossws = ws + WS_PL;
    float*  rfeat   = ws + WS_RF;

    node_precompute<<<dim3((NTILE64 + 3) / 4), dim3(256), 0, stream>>>(
        features, rsim, pos_embs, node_sc);
    relation_agg<<<dim3(BN / 4, 3), dim3(256), 0, stream>>>(
        neigh1, neigh2, neigh3, features, node_sc, W1, W2, W3,
        pos_embs, plossws, rfeat, smp);
    final_mm<<<dim3(BN / 8), dim3(256), 0, stream>>>(
        nodes, features, rfeat, weight, pos_embs, pos_nodes,
        node_sc, plossws, smp, out);
}